// Round 12
// baseline (3041.994 us; speedup 1.0000x reference)
//
#include <hip/hip_runtime.h>
#include <hip/hip_fp16.h>

namespace {

constexpr int kS = 1024;   // SEQ
constexpr int kI = 64;     // INPUT_SIZE
constexpr int kH = 128;    // HIDDEN

typedef _Float16 f16x8 __attribute__((ext_vector_type(8)));
typedef float    f32x4 __attribute__((ext_vector_type(4)));

#define MFMA16(a, b, c) __builtin_amdgcn_mfma_f32_16x16x32_f16((a), (b), (c), 0, 0, 0)

__device__ __forceinline__ float rcpf(float x) {
#if __has_builtin(__builtin_amdgcn_rcpf)
  return __builtin_amdgcn_rcpf(x);
#else
  return 1.0f / x;
#endif
}
__device__ __forceinline__ float sigf(float x)  { return rcpf(1.0f + __expf(-x)); }
__device__ __forceinline__ float tanhff(float x){ return 1.0f - 2.0f * rcpf(1.0f + __expf(2.0f * x)); }

// A fragment: lane (q=lane>>4, j=lane&15) holds W[row][k0..k0+7]. A and B use
// the same k-chunk packing (HW k-permutation cancels); C/D mapping
// (col=lane&15, row=4*(lane>>4)+reg) is the only load-bearing layout.
__device__ __forceinline__ f16x8 afrag(const float* __restrict__ W, int row,
                                       int k0, int ld) {
  const float4* p = reinterpret_cast<const float4*>(W + (size_t)row * ld + k0);
  const float4 u = p[0], v = p[1];
  f16x8 a;
  a[0] = (_Float16)u.x; a[1] = (_Float16)u.y; a[2] = (_Float16)u.z; a[3] = (_Float16)u.w;
  a[4] = (_Float16)v.x; a[5] = (_Float16)v.y; a[6] = (_Float16)v.z; a[7] = (_Float16)v.w;
  return a;
}

// Fused 2-layer LSTM, software-pipelined by one 8-step tile.
// 256 blocks x 1024 thr (16 waves), chains b0,b0+1.
// Waves 0-7: layer 1 (Wh1 resident). Waves 8-15: layer 2 (Wh2 resident).
// Super-step t: l1 step t and l2 step t-8 run in parallel (independent).
// Per tile: batched GEMMs Wx1.x(T) / Wx2.h1(T-1) fill xg1/xg2 (16 real cols).
// Activation: waves 0-3 -> l1 cells, waves 8-11 -> l2 cells (LDS-style).
__global__ __launch_bounds__(1024, 1) __attribute__((amdgpu_waves_per_eu(4, 4)))
void lstm_fused(
    const float* __restrict__ x,
    const float* __restrict__ Wx1, const float* __restrict__ bx1,
    const float* __restrict__ Wh1, const float* __restrict__ bh1,
    const float* __restrict__ Wx2, const float* __restrict__ bx2,
    const float* __restrict__ Wh2, const float* __restrict__ bh2,
    const float* __restrict__ Wc,  const float* __restrict__ bc,
    float* __restrict__ out)
{
  const int tid  = threadIdx.x;
  const int b0   = blockIdx.x * 2;
  const int w    = tid >> 6;
  const int lane = tid & 63;
  const int q    = lane >> 4;
  const int n    = lane & 15;
  const int lw   = w & 7;              // wave index within layer group
  const bool isL2w = (w >= 8);
  const int csel = (n < 2) ? n : 0;    // pad cols broadcast chain 0

  __shared__ __align__(16) _Float16 xF[8][17][8];       // [kc][col][e] 2.1 KiB
  __shared__ __align__(16) _Float16 h1R[2][16][17][8];  // [buf][kc][col][e] 8.5 KiB
  __shared__ __align__(16) _Float16 h2B[2][2][16][8];   // [par][c][kc][e] 1 KiB
  __shared__ float xg1[16][516];                        // 33 KiB
  __shared__ float xg2[16][516];                        // 33 KiB
  __shared__ float g1[2][512];                          // 4 KiB
  __shared__ float g2[2][512];                          // 4 KiB
  __shared__ float hfin[2][128];                        // 1 KiB

  // resident recurrent weights: wave's 4 M-tiles (rows 64*lw .. 64*lw+63)
  f16x8 Ah[4][4];
  {
    const float* Wr = isL2w ? Wh2 : Wh1;
#pragma unroll
    for (int i = 0; i < 4; ++i)
#pragma unroll
      for (int kt = 0; kt < 4; ++kt)
        Ah[i][kt] = afrag(Wr, (lw * 4 + i) * 16 + n, kt * 32 + q * 8, kH);
  }

  // activation-role biases (role A: tid<256 l1 cell; role B: 512<=tid<768 l2)
  float bI = 0.f, bF = 0.f, bG = 0.f, bO = 0.f, cst = 0.f;
  if (tid < 256) {
    const int j = tid & 127;
    bI = bx1[j]       + bh1[j];
    bF = bx1[j + 128] + bh1[j + 128];
    bG = bx1[j + 256] + bh1[j + 256];
    bO = bx1[j + 384] + bh1[j + 384];
  } else if (tid >= 512 && tid < 768) {
    const int j = tid & 127;
    bI = bx2[j]       + bh2[j];
    bF = bx2[j + 128] + bh2[j + 128];
    bG = bx2[j + 256] + bh2[j + 256];
    bO = bx2[j + 384] + bh2[j + 384];
  }

  // zero-init h1R buffer 1 (h1(-1) slot) and h2B (h2(-1))
  for (int i = tid; i < 16 * 17 * 8; i += 1024)
    (&h1R[1][0][0][0])[i] = (_Float16)0.f;
  if (tid < 512) (&h2B[0][0][0][0])[tid] = (_Float16)0.f;

  for (int T = 0; T < 129; ++T) {
    const bool hasL1 = (T < 128);
    const bool hasL2 = (T > 0);

    // ---- stage x tile T (1024 scalar loads, coalesced 64-float runs) ----
    if (hasL1) {
      const int col = tid >> 6, k = tid & 63;   // col = dt*2+c
      const int c = col & 1, dt = col >> 1;
      xF[k >> 3][col][k & 7] =
          (_Float16)x[((size_t)(b0 + c) * kS + (size_t)(T * 8 + dt)) * kI + k];
    }
    __syncthreads();

    // ---- batched GEMM phase ----
    if (!isL2w && hasL1) {          // xg1 = Wx1 . x(T)
      f32x4 e0 = {0,0,0,0}, e1 = {0,0,0,0}, e2 = {0,0,0,0}, e3 = {0,0,0,0};
      const char* xb = reinterpret_cast<const char*>(&xF[0][0][0]);
#pragma unroll
      for (int kt = 0; kt < 2; ++kt) {
        const f16x8 bf = *reinterpret_cast<const f16x8*>(
            xb + (((kt * 4 + q) * 17 + n) << 4));
        e0 = MFMA16(afrag(Wx1, (lw*4+0)*16 + n, kt*32 + q*8, kI), bf, e0);
        e1 = MFMA16(afrag(Wx1, (lw*4+1)*16 + n, kt*32 + q*8, kI), bf, e1);
        e2 = MFMA16(afrag(Wx1, (lw*4+2)*16 + n, kt*32 + q*8, kI), bf, e2);
        e3 = MFMA16(afrag(Wx1, (lw*4+3)*16 + n, kt*32 + q*8, kI), bf, e3);
      }
      *reinterpret_cast<f32x4*>(&xg1[n][(lw*4+0)*16 + q*4]) = e0;
      *reinterpret_cast<f32x4*>(&xg1[n][(lw*4+1)*16 + q*4]) = e1;
      *reinterpret_cast<f32x4*>(&xg1[n][(lw*4+2)*16 + q*4]) = e2;
      *reinterpret_cast<f32x4*>(&xg1[n][(lw*4+3)*16 + q*4]) = e3;
    }
    if (isL2w && hasL2) {           // xg2 = Wx2 . h1(tile T-1)
      f32x4 e0 = {0,0,0,0}, e1 = {0,0,0,0}, e2 = {0,0,0,0}, e3 = {0,0,0,0};
      const char* hb = reinterpret_cast<const char*>(&h1R[(T + 1) & 1][0][0][0]);
#pragma unroll
      for (int kt = 0; kt < 4; ++kt) {
        const f16x8 bf = *reinterpret_cast<const f16x8*>(
            hb + (((kt * 4 + q) * 17 + n) << 4));
        e0 = MFMA16(afrag(Wx2, (lw*4+0)*16 + n, kt*32 + q*8, kH), bf, e0);
        e1 = MFMA16(afrag(Wx2, (lw*4+1)*16 + n, kt*32 + q*8, kH), bf, e1);
        e2 = MFMA16(afrag(Wx2, (lw*4+2)*16 + n, kt*32 + q*8, kH), bf, e2);
        e3 = MFMA16(afrag(Wx2, (lw*4+3)*16 + n, kt*32 + q*8, kH), bf, e3);
      }
      *reinterpret_cast<f32x4*>(&xg2[n][(lw*4+0)*16 + q*4]) = e0;
      *reinterpret_cast<f32x4*>(&xg2[n][(lw*4+1)*16 + q*4]) = e1;
      *reinterpret_cast<f32x4*>(&xg2[n][(lw*4+2)*16 + q*4]) = e2;
      *reinterpret_cast<f32x4*>(&xg2[n][(lw*4+3)*16 + q*4]) = e3;
    }
    __syncthreads();

    // ---- 8 fused super-steps ----
    for (int dt = 0; dt < 8; ++dt) {
      const int t  = T * 8 + dt;     // l1 step
      const int t2 = t - 8;          // l2 step

      if (!isL2w && hasL1) {         // l1 recurrent: B = h1(t-1)
        const int rb  = (dt == 0) ? ((T + 1) & 1) : (T & 1);
        const int col = (dt == 0) ? (14 + csel) : ((dt - 1) * 2 + csel);
        const char* hb = reinterpret_cast<const char*>(&h1R[rb][0][0][0]) + col * 16;
        f32x4 d0 = {0,0,0,0}, d1 = {0,0,0,0}, d2 = {0,0,0,0}, d3 = {0,0,0,0};
#pragma unroll
        for (int kt = 0; kt < 4; ++kt) {
          const f16x8 bf = *reinterpret_cast<const f16x8*>(hb + (kt * 4 + q) * 272);
          d0 = MFMA16(Ah[0][kt], bf, d0);  d1 = MFMA16(Ah[1][kt], bf, d1);
          d2 = MFMA16(Ah[2][kt], bf, d2);  d3 = MFMA16(Ah[3][kt], bf, d3);
        }
        if (n < 2) {
          *reinterpret_cast<f32x4*>(&g1[n][(lw*4+0)*16 + q*4]) = d0;
          *reinterpret_cast<f32x4*>(&g1[n][(lw*4+1)*16 + q*4]) = d1;
          *reinterpret_cast<f32x4*>(&g1[n][(lw*4+2)*16 + q*4]) = d2;
          *reinterpret_cast<f32x4*>(&g1[n][(lw*4+3)*16 + q*4]) = d3;
        }
      }
      if (isL2w && hasL2) {          // l2 recurrent: B = h2(t2-1)
        const char* hb = reinterpret_cast<const char*>(&h2B[(t2 + 1) & 1][csel][0][0]);
        f32x4 d0 = {0,0,0,0}, d1 = {0,0,0,0}, d2 = {0,0,0,0}, d3 = {0,0,0,0};
#pragma unroll
        for (int kt = 0; kt < 4; ++kt) {
          const f16x8 bf = *reinterpret_cast<const f16x8*>(hb + ((kt * 4 + q) << 4));
          d0 = MFMA16(Ah[0][kt], bf, d0);  d1 = MFMA16(Ah[1][kt], bf, d1);
          d2 = MFMA16(Ah[2][kt], bf, d2);  d3 = MFMA16(Ah[3][kt], bf, d3);
        }
        if (n < 2) {
          *reinterpret_cast<f32x4*>(&g2[n][(lw*4+0)*16 + q*4]) = d0;
          *reinterpret_cast<f32x4*>(&g2[n][(lw*4+1)*16 + q*4]) = d1;
          *reinterpret_cast<f32x4*>(&g2[n][(lw*4+2)*16 + q*4]) = d2;
          *reinterpret_cast<f32x4*>(&g2[n][(lw*4+3)*16 + q*4]) = d3;
        }
      }
      __syncthreads();

      if (tid < 256 && hasL1) {      // l1 activation (1 cell/lane)
        const int c = tid >> 7, j = tid & 127, col = dt * 2 + c;
        const float gi = xg1[col][j]       + g1[c][j]       + bI;
        const float gf = xg1[col][j + 128] + g1[c][j + 128] + bF;
        const float gg = xg1[col][j + 256] + g1[c][j + 256] + bG;
        const float go = xg1[col][j + 384] + g1[c][j + 384] + bO;
        cst = sigf(gf) * cst + sigf(gi) * tanhff(gg);
        h1R[T & 1][j >> 3][col][j & 7] = (_Float16)(sigf(go) * tanhff(cst));
      } else if (tid >= 512 && tid < 768 && hasL2) {   // l2 activation
        const int c = (tid >> 7) & 1, j = tid & 127, col = dt * 2 + c;
        const float gi = xg2[col][j]       + g2[c][j]       + bI;
        const float gf = xg2[col][j + 128] + g2[c][j + 128] + bF;
        const float gg = xg2[col][j + 256] + g2[c][j + 256] + bG;
        const float go = xg2[col][j + 384] + g2[c][j + 384] + bO;
        cst = sigf(gf) * cst + sigf(gi) * tanhff(gg);
        const float h = sigf(go) * tanhff(cst);
        h2B[t2 & 1][c][j >> 3][j & 7] = (_Float16)h;
        if (t2 == kS - 1) hfin[c][j] = h;
      }
      __syncthreads();
    }
  }

  // classifier head: logits[b0+c, m] = Wc[m,:] . h2fin[c] + bc[m]
  if (tid < 8) {
    const int m = tid & 3, c = tid >> 2;
    const float* wr = Wc + (size_t)m * kH;
    float s0 = 0.f, s1 = 0.f, s2 = 0.f, s3 = 0.f;
#pragma unroll
    for (int j = 0; j < kH; j += 4) {
      s0 = fmaf(wr[j],     hfin[c][j],     s0);
      s1 = fmaf(wr[j + 1], hfin[c][j + 1], s1);
      s2 = fmaf(wr[j + 2], hfin[c][j + 2], s2);
      s3 = fmaf(wr[j + 3], hfin[c][j + 3], s3);
    }
    out[(size_t)(b0 + c) * 4 + m] = bc[m] + ((s0 + s1) + (s2 + s3));
  }
}

} // namespace

extern "C" void kernel_launch(void* const* d_in, const int* in_sizes, int n_in,
                              void* d_out, int out_size, void* d_ws, size_t ws_size,
                              hipStream_t stream) {
  const float* x   = (const float*)d_in[0];
  const float* Wx1 = (const float*)d_in[1];
  const float* bx1 = (const float*)d_in[2];
  const float* Wh1 = (const float*)d_in[3];
  const float* bh1 = (const float*)d_in[4];
  const float* Wx2 = (const float*)d_in[5];
  const float* bx2 = (const float*)d_in[6];
  const float* Wh2 = (const float*)d_in[7];
  const float* bh2 = (const float*)d_in[8];
  const float* Wc  = (const float*)d_in[9];
  const float* bc  = (const float*)d_in[10];

  hipLaunchKernelGGL(lstm_fused, dim3(256), dim3(1024), 0, stream,
                     x, Wx1, bx1, Wh1, bh1, Wx2, bx2, Wh2, bh2, Wc, bc,
                     (float*)d_out);
}

// Round 13
// 2707.864 us; speedup vs baseline: 1.1234x; 1.1234x over previous
//
#include <hip/hip_runtime.h>
#include <hip/hip_fp16.h>

namespace {

constexpr int kS  = 1024;   // SEQ
constexpr int kI  = 64;     // INPUT_SIZE
constexpr int kH  = 128;    // HIDDEN
constexpr int kTT = 16;     // steps per tile (= MFMA N), 64 tiles

typedef _Float16 f16x8 __attribute__((ext_vector_type(8)));
typedef float    f32x4 __attribute__((ext_vector_type(4)));

#define MFMA16(a, b, c) __builtin_amdgcn_mfma_f32_16x16x32_f16((a), (b), (c), 0, 0, 0)

__device__ __forceinline__ float rcpf(float x) {
#if __has_builtin(__builtin_amdgcn_rcpf)
  return __builtin_amdgcn_rcpf(x);
#else
  return 1.0f / x;
#endif
}
__device__ __forceinline__ float sigf(float x)  { return rcpf(1.0f + __expf(-x)); }
__device__ __forceinline__ float tanhff(float x){ return 1.0f - 2.0f * rcpf(1.0f + __expf(2.0f * x)); }

template <int P>
__device__ __forceinline__ void prio() {
#if __has_builtin(__builtin_amdgcn_s_setprio)
  __builtin_amdgcn_s_setprio(P);
#endif
}

__device__ __forceinline__ unsigned packf2(float lo, float hi) {
  _Float16 a = (_Float16)lo, b = (_Float16)hi;
  unsigned short ua = __builtin_bit_cast(unsigned short, a);
  unsigned short ub = __builtin_bit_cast(unsigned short, b);
  return (unsigned)ua | ((unsigned)ub << 16);
}

// A fragment: lane (q=lane>>4, j=lane&15) holds W[row][k0..k0+7]. A and B use
// the same k-chunk packing (HW k-permutation cancels); C/D mapping
// (col=lane&15, row=4*(lane>>4)+reg) is the only load-bearing layout.
__device__ __forceinline__ f16x8 afrag(const float* __restrict__ W, int row,
                                       int k0, int ld) {
  const float4* p = reinterpret_cast<const float4*>(W + (size_t)row * ld + k0);
  const float4 u = p[0], v = p[1];
  f16x8 a;
  a[0] = (_Float16)u.x; a[1] = (_Float16)u.y; a[2] = (_Float16)u.z; a[3] = (_Float16)u.w;
  a[4] = (_Float16)v.x; a[5] = (_Float16)v.y; a[6] = (_Float16)v.z; a[7] = (_Float16)v.w;
  return a;
}

// ---------------- K1: layer 1, 1 chain/block ----------------
// 512 blocks x 512 thr (8 waves); launch_bounds(512,2) -> cap 128 VGPR and
// 2 blocks/CU co-resident (cross-block stall hiding). Wave w owns M-tiles
// 4w..4w+3; Ah resident (16 frags = 64 VGPR), Ax streamed per tile.
__global__ __launch_bounds__(512, 2) void lstm_l1(
    const float* __restrict__ x, const float* __restrict__ Wx1,
    const float* __restrict__ bx1, const float* __restrict__ Wh1,
    const float* __restrict__ bh1, _Float16* __restrict__ h1out)
{
  const int tid  = threadIdx.x;
  const int b    = blockIdx.x;
  const int w    = tid >> 6;
  const int lane = tid & 63;
  const int q    = lane >> 4;
  const int n    = lane & 15;

  __shared__ __align__(16) _Float16 xF[8][kTT][8];        // [kc][col=dt][e] 2 KiB
  __shared__ __align__(16) _Float16 hH[2][kTT][16][8];    // tile h history 8 KiB
  __shared__ float xg[kTT][516];                          // [col][row] 33 KiB
  __shared__ float g[512];                                // recurrent preacts 2 KiB

  f16x8 Ah[4][4];
#pragma unroll
  for (int i = 0; i < 4; ++i)
#pragma unroll
    for (int kt = 0; kt < 4; ++kt)
      Ah[i][kt] = afrag(Wh1, (w * 4 + i) * 16 + n, kt * 32 + q * 8, kH);

  float bI = 0.f, bF = 0.f, bG = 0.f, bO = 0.f, cst = 0.f;
  if (tid < 128) {
    bI = bx1[tid]       + bh1[tid];
    bF = bx1[tid + 128] + bh1[tid + 128];
    bG = bx1[tid + 256] + bh1[tid + 256];
    bO = bx1[tid + 384] + bh1[tid + 384];
    reinterpret_cast<_Float16*>(&hH[1][kTT - 1][0][0])[tid] = (_Float16)0.f; // h(-1)
  }

  for (int T = 0; T < kS / kTT; ++T) {
    {  // stage x tile: 16 steps x 64 in, float2 loads (coalesced)
      const int dt = tid >> 5, k = (tid & 31) * 2;
      const float2 v = *reinterpret_cast<const float2*>(
          x + ((size_t)b * kS + (size_t)(T * kTT + dt)) * kI + k);
      *reinterpret_cast<unsigned*>(&xF[k >> 3][dt][k & 7]) = packf2(v.x, v.y);
    }
    __syncthreads();

    {  // batched GEMM: xg[col][row] = Wx1[row,:] . x(col); Ax streamed
      const char* xb = reinterpret_cast<const char*>(&xF[0][0][0]);
      f32x4 e0 = {0,0,0,0}, e1 = {0,0,0,0}, e2 = {0,0,0,0}, e3 = {0,0,0,0};
#pragma unroll
      for (int kt = 0; kt < 2; ++kt) {
        const f16x8 bf = *reinterpret_cast<const f16x8*>(
            xb + (((kt * 4 + q) * kTT + n) << 4));
        e0 = MFMA16(afrag(Wx1, (w*4+0)*16 + n, kt*32 + q*8, kI), bf, e0);
        e1 = MFMA16(afrag(Wx1, (w*4+1)*16 + n, kt*32 + q*8, kI), bf, e1);
        e2 = MFMA16(afrag(Wx1, (w*4+2)*16 + n, kt*32 + q*8, kI), bf, e2);
        e3 = MFMA16(afrag(Wx1, (w*4+3)*16 + n, kt*32 + q*8, kI), bf, e3);
      }
      *reinterpret_cast<f32x4*>(&xg[n][(w*4+0)*16 + q*4]) = e0;
      *reinterpret_cast<f32x4*>(&xg[n][(w*4+1)*16 + q*4]) = e1;
      *reinterpret_cast<f32x4*>(&xg[n][(w*4+2)*16 + q*4]) = e2;
      *reinterpret_cast<f32x4*>(&xg[n][(w*4+3)*16 + q*4]) = e3;
    }
    __syncthreads();

    for (int dt = 0; dt < kTT; ++dt) {
      const char* hb = (dt == 0)
          ? reinterpret_cast<const char*>(&hH[(T + 1) & 1][kTT - 1][0][0])
          : reinterpret_cast<const char*>(&hH[T & 1][dt - 1][0][0]);

      f32x4 d0 = {0,0,0,0}, d1 = {0,0,0,0}, d2 = {0,0,0,0}, d3 = {0,0,0,0};
      prio<1>();
#pragma unroll
      for (int kt = 0; kt < 4; ++kt) {   // broadcast 16B per q-group
        const f16x8 bf = *reinterpret_cast<const f16x8*>(hb + ((kt * 4 + q) << 4));
        d0 = MFMA16(Ah[0][kt], bf, d0);  d1 = MFMA16(Ah[1][kt], bf, d1);
        d2 = MFMA16(Ah[2][kt], bf, d2);  d3 = MFMA16(Ah[3][kt], bf, d3);
      }
      prio<0>();

      if (n == 0) {
        *reinterpret_cast<f32x4*>(&g[(w*4+0)*16 + q*4]) = d0;
        *reinterpret_cast<f32x4*>(&g[(w*4+1)*16 + q*4]) = d1;
        *reinterpret_cast<f32x4*>(&g[(w*4+2)*16 + q*4]) = d2;
        *reinterpret_cast<f32x4*>(&g[(w*4+3)*16 + q*4]) = d3;
      }
      __syncthreads();

      if (tid < 128) {   // activation: 1 cell/thread, dense 2 waves
        const int j = tid;
        const float gi = xg[dt][j]       + g[j]       + bI;
        const float gf = xg[dt][j + 128] + g[j + 128] + bF;
        const float gg = xg[dt][j + 256] + g[j + 256] + bG;
        const float go = xg[dt][j + 384] + g[j + 384] + bO;
        cst = sigf(gf) * cst + sigf(gi) * tanhff(gg);
        hH[T & 1][dt][j >> 3][j & 7] = (_Float16)(sigf(go) * tanhff(cst));
      }
      __syncthreads();
    }

    {  // dump tile's h to global (2048 fp16, 512 thr x uint2, coalesced)
      const uint2 v = reinterpret_cast<const uint2*>(&hH[T & 1][0][0][0])[tid];
      *reinterpret_cast<uint2*>(
          h1out + ((size_t)b * kS + (size_t)(T * kTT)) * kH + tid * 4) = v;
    }
  }
}

// ---------------- K2: layer 2 + head, 1 chain/block ----------------
__global__ __launch_bounds__(512, 2) void lstm_l2(
    const _Float16* __restrict__ h1in,
    const float* __restrict__ Wx2, const float* __restrict__ bx2,
    const float* __restrict__ Wh2, const float* __restrict__ bh2,
    const float* __restrict__ Wc,  const float* __restrict__ bc,
    float* __restrict__ out)
{
  const int tid  = threadIdx.x;
  const int b    = blockIdx.x;
  const int w    = tid >> 6;
  const int lane = tid & 63;
  const int q    = lane >> 4;
  const int n    = lane & 15;

  __shared__ __align__(16) _Float16 h1F[16][kTT][8];      // [kc][col][e] 4 KiB
  __shared__ __align__(16) _Float16 h2B[2][16][8];        // parity dbuf 512 B
  __shared__ float xg[kTT][516];                          // 33 KiB
  __shared__ float g[512];                                // 2 KiB
  __shared__ float hfin[128];

  f16x8 Ah[4][4];
#pragma unroll
  for (int i = 0; i < 4; ++i)
#pragma unroll
    for (int kt = 0; kt < 4; ++kt)
      Ah[i][kt] = afrag(Wh2, (w * 4 + i) * 16 + n, kt * 32 + q * 8, kH);

  float bI = 0.f, bF = 0.f, bG = 0.f, bO = 0.f, cst = 0.f;
  if (tid < 128) {
    bI = bx2[tid]       + bh2[tid];
    bF = bx2[tid + 128] + bh2[tid + 128];
    bG = bx2[tid + 256] + bh2[tid + 256];
    bO = bx2[tid + 384] + bh2[tid + 384];
    reinterpret_cast<_Float16*>(&h2B[1][0][0])[tid] = (_Float16)0.f;  // h2(-1)
  }

  for (int T = 0; T < kS / kTT; ++T) {
    {  // stage h1 tile: uint2 loads (coalesced)
      const int dt = tid >> 5, k = (tid & 31) * 4;
      const uint2 v = *reinterpret_cast<const uint2*>(
          h1in + ((size_t)b * kS + (size_t)(T * kTT + dt)) * kH + k);
      *reinterpret_cast<uint2*>(&h1F[k >> 3][dt][k & 7]) = v;
    }
    __syncthreads();

    {  // batched GEMM: xg = Wx2 . h1(tile); Ax streamed
      const char* xb = reinterpret_cast<const char*>(&h1F[0][0][0]);
      f32x4 e0 = {0,0,0,0}, e1 = {0,0,0,0}, e2 = {0,0,0,0}, e3 = {0,0,0,0};
#pragma unroll
      for (int kt = 0; kt < 4; ++kt) {
        const f16x8 bf = *reinterpret_cast<const f16x8*>(
            xb + (((kt * 4 + q) * kTT + n) << 4));
        e0 = MFMA16(afrag(Wx2, (w*4+0)*16 + n, kt*32 + q*8, kH), bf, e0);
        e1 = MFMA16(afrag(Wx2, (w*4+1)*16 + n, kt*32 + q*8, kH), bf, e1);
        e2 = MFMA16(afrag(Wx2, (w*4+2)*16 + n, kt*32 + q*8, kH), bf, e2);
        e3 = MFMA16(afrag(Wx2, (w*4+3)*16 + n, kt*32 + q*8, kH), bf, e3);
      }
      *reinterpret_cast<f32x4*>(&xg[n][(w*4+0)*16 + q*4]) = e0;
      *reinterpret_cast<f32x4*>(&xg[n][(w*4+1)*16 + q*4]) = e1;
      *reinterpret_cast<f32x4*>(&xg[n][(w*4+2)*16 + q*4]) = e2;
      *reinterpret_cast<f32x4*>(&xg[n][(w*4+3)*16 + q*4]) = e3;
    }
    __syncthreads();

    for (int dt = 0; dt < kTT; ++dt) {
      const int t = T * kTT + dt;
      const char* hb = reinterpret_cast<const char*>(&h2B[(t + 1) & 1][0][0]);

      f32x4 d0 = {0,0,0,0}, d1 = {0,0,0,0}, d2 = {0,0,0,0}, d3 = {0,0,0,0};
      prio<1>();
#pragma unroll
      for (int kt = 0; kt < 4; ++kt) {
        const f16x8 bf = *reinterpret_cast<const f16x8*>(hb + ((kt * 4 + q) << 4));
        d0 = MFMA16(Ah[0][kt], bf, d0);  d1 = MFMA16(Ah[1][kt], bf, d1);
        d2 = MFMA16(Ah[2][kt], bf, d2);  d3 = MFMA16(Ah[3][kt], bf, d3);
      }
      prio<0>();

      if (n == 0) {
        *reinterpret_cast<f32x4*>(&g[(w*4+0)*16 + q*4]) = d0;
        *reinterpret_cast<f32x4*>(&g[(w*4+1)*16 + q*4]) = d1;
        *reinterpret_cast<f32x4*>(&g[(w*4+2)*16 + q*4]) = d2;
        *reinterpret_cast<f32x4*>(&g[(w*4+3)*16 + q*4]) = d3;
      }
      __syncthreads();

      if (tid < 128) {
        const int j = tid;
        const float gi = xg[dt][j]       + g[j]       + bI;
        const float gf = xg[dt][j + 128] + g[j + 128] + bF;
        const float gg = xg[dt][j + 256] + g[j + 256] + bG;
        const float go = xg[dt][j + 384] + g[j + 384] + bO;
        cst = sigf(gf) * cst + sigf(gi) * tanhff(gg);
        const float h = sigf(go) * tanhff(cst);
        h2B[t & 1][j >> 3][j & 7] = (_Float16)h;
        if (t == kS - 1) hfin[j] = h;
      }
      __syncthreads();
    }
  }

  // classifier head: logits[b, m] = Wc[m,:] . h2fin + bc[m]
  if (tid < 4) {
    const float* wr = Wc + (size_t)tid * kH;
    float s0 = 0.f, s1 = 0.f, s2 = 0.f, s3 = 0.f;
#pragma unroll
    for (int j = 0; j < kH; j += 4) {
      s0 = fmaf(wr[j],     hfin[j],     s0);
      s1 = fmaf(wr[j + 1], hfin[j + 1], s1);
      s2 = fmaf(wr[j + 2], hfin[j + 2], s2);
      s3 = fmaf(wr[j + 3], hfin[j + 3], s3);
    }
    out[(size_t)b * 4 + tid] = bc[tid] + ((s0 + s1) + (s2 + s3));
  }
}

} // namespace

extern "C" void kernel_launch(void* const* d_in, const int* in_sizes, int n_in,
                              void* d_out, int out_size, void* d_ws, size_t ws_size,
                              hipStream_t stream) {
  const float* x   = (const float*)d_in[0];
  const float* Wx1 = (const float*)d_in[1];
  const float* bx1 = (const float*)d_in[2];
  const float* Wh1 = (const float*)d_in[3];
  const float* bh1 = (const float*)d_in[4];
  const float* Wx2 = (const float*)d_in[5];
  const float* bx2 = (const float*)d_in[6];
  const float* Wh2 = (const float*)d_in[7];
  const float* bh2 = (const float*)d_in[8];
  const float* Wc  = (const float*)d_in[9];
  const float* bc  = (const float*)d_in[10];

  _Float16* h1 = (_Float16*)d_ws;   // 512*1024*128 fp16 = 128 MiB layer-1 stream

  hipLaunchKernelGGL(lstm_l1, dim3(512), dim3(512), 0, stream,
                     x, Wx1, bx1, Wh1, bh1, h1);
  hipLaunchKernelGGL(lstm_l2, dim3(512), dim3(512), 0, stream,
                     h1, Wx2, bx2, Wh2, bh2, Wc, bc, (float*)d_out);
}